// Round 6
// baseline (533.984 us; speedup 1.0000x reference)
//
#include <hip/hip_runtime.h>
#include <hip/hip_bf16.h>
#include <hip/hip_cooperative_groups.h>
#include <stdint.h>

namespace cg = cooperative_groups;

#define NN 50000     // nodes
#define NE 640000    // edges
#define NR 8         // relations
#define NK (NR * NN) // 400000 (rel,dst) keys
#define NPB 391      // prep blocks = ceil(NK/1024)

typedef short bf16x8 __attribute__((ext_vector_type(8)));
typedef float f32x4  __attribute__((ext_vector_type(4)));

__device__ __forceinline__ unsigned short f2bf(float f) {
    union { float f; unsigned u; } v; v.f = f;
    unsigned r = v.u + 0x7FFF + ((v.u >> 16) & 1);
    return (unsigned short)(r >> 16);
}

// ---------------- single cooperative prep kernel ----------------
// Replaces: memset, hist2, blocksum, scanbase, scanlocal, fill2, cvt_bf16,
// prepW<128>, prepW<64>  (9 launches -> 1).
// Grid: NPB=391 blocks x 1024 threads (co-resident: 2 blocks/CU via
// __launch_bounds__(1024,8); 391 <= 512).
__global__ __launch_bounds__(1024, 8) void prep_all(
        const float* __restrict__ X,
        const float* __restrict__ W1, const float* __restrict__ W1s,
        const float* __restrict__ W2, const float* __restrict__ W2s,
        const int* __restrict__ src, const int* __restrict__ dst,
        const int* __restrict__ et,
        unsigned short* __restrict__ Xbf,
        unsigned short* __restrict__ W1T, unsigned short* __restrict__ W2T,
        int* __restrict__ counts, int* __restrict__ off2,
        int* __restrict__ cursor, int* __restrict__ esrc,
        int* __restrict__ bsum, int* __restrict__ bbase) {
    cg::grid_group grid = cg::this_grid();
    const int t = threadIdx.x, b = blockIdx.x;
    const int gid = b * 1024 + t;
    const int gsz = gridDim.x * 1024;   // 400384
    const int lane = t & 63, wid = t >> 6;
    __shared__ int ws[16];
    __shared__ int wbase[16];

    // ---- P0: zero counts; cvt X->bf16; build W1T/W2T (independent work) ----
    for (int i = gid; i < NK; i += gsz) counts[i] = 0;
    for (int i = gid; i < NN * 16; i += gsz) {   // 800000 units of 8 floats
        const float4* pp = (const float4*)X + (size_t)i * 2;
        float4 a = pp[0], c = pp[1];
        uint4 o;
        o.x = (unsigned)f2bf(a.x) | ((unsigned)f2bf(a.y) << 16);
        o.y = (unsigned)f2bf(a.z) | ((unsigned)f2bf(a.w) << 16);
        o.z = (unsigned)f2bf(c.x) | ((unsigned)f2bf(c.y) << 16);
        o.w = (unsigned)f2bf(c.z) | ((unsigned)f2bf(c.w) << 16);
        ((uint4*)Xbf)[i] = o;
    }
    for (int i = gid; i < 9 * 128 * 128; i += gsz) {   // W1T
        int k = i & 127, c = i >> 7;
        int r = c >> 7, o = c & 127;
        float v = (r < 8) ? W1[((size_t)r * 128 + k) * 128 + o]
                          : W1s[(size_t)k * 128 + o];
        W1T[i] = f2bf(v);
    }
    for (int i = gid; i < 9 * 64 * 128; i += gsz) {    // W2T
        int k = i & 127, c = i >> 7;
        int r = c >> 6, o = c & 63;
        float v = (r < 8) ? W2[((size_t)r * 128 + k) * 64 + o]
                          : W2s[(size_t)k * 64 + o];
        W2T[i] = f2bf(v);
    }
    grid.sync();

    // ---- P1: histogram over (rel,dst) keys ----
    for (int e = gid; e < NE; e += gsz)
        atomicAdd(&counts[et[e] * NN + dst[e]], 1);
    grid.sync();

    // ---- P2: per-block local exclusive scan (this block owns chunk b) ----
    int i2 = b * 1024 + t;
    int v = (i2 < NK) ? counts[i2] : 0;
    int incl = v;
    #pragma unroll
    for (int d = 1; d < 64; d <<= 1) {
        int nv = __shfl_up(incl, d, 64);
        if (lane >= d) incl += nv;
    }
    if (lane == 63) ws[wid] = incl;
    __syncthreads();
    if (t < 16) {
        int s = ws[t], si = s;
        #pragma unroll
        for (int d = 1; d < 16; d <<= 1) {
            int nv = __shfl_up(si, d, 16);
            if (t >= d) si += nv;
        }
        wbase[t] = si - s;   // exclusive wave base
    }
    __syncthreads();
    int local_excl = wbase[wid] + incl - v;     // persists in registers
    if (t == 0) bsum[b] = wbase[15] + ws[15];   // block total
    grid.sync();

    // ---- P3: block 0 scans the 391 block sums -> exclusive bases ----
    if (b == 0) {
        int nb = gridDim.x;
        int vv = (t < nb) ? bsum[t] : 0;
        int inc2 = vv;
        #pragma unroll
        for (int d = 1; d < 64; d <<= 1) {
            int nv = __shfl_up(inc2, d, 64);
            if (lane >= d) inc2 += nv;
        }
        if (lane == 63) ws[wid] = inc2;
        __syncthreads();
        if (t < 16) {
            int s = ws[t], si = s;
            #pragma unroll
            for (int d = 1; d < 16; d <<= 1) {
                int nv = __shfl_up(si, d, 16);
                if (t >= d) si += nv;
            }
            wbase[t] = si - s;
        }
        __syncthreads();
        if (t < nb) bbase[t] = wbase[wid] + inc2 - vv;
    }
    grid.sync();

    // ---- P4: apply bases -> offsets + cursor ----
    if (i2 < NK) {
        int e2 = bbase[b] + local_excl;
        off2[i2] = e2;
        cursor[i2] = e2;
    }
    if (gid == 0) off2[NK] = NE;
    grid.sync();

    // ---- P5: fill esrc (sorted by (rel,dst)) ----
    for (int e = gid; e < NE; e += gsz) {
        int pos = atomicAdd(&cursor[et[e] * NN + dst[e]], 1);
        esrc[pos] = src[e];
    }
}

// ---------------- Fused aggregate + transform layer ----------------
// Proven RB=64 shape (301.7 us baseline). Per block: 64 dst nodes, 256
// threads. Edges sorted by (rel,dst): atomic-free aggregation. Thread t owns
// dst row (t>>2), column group (t&3): 32 cols in registers over its segment,
// packed to bf16 into the XOR-swizzled Asw. MFMA-accumulates
// C[64][NOUT] += agg_r @ W[r]^T across r=0..7 plus self (idx 8).
template<int NOUT, bool RELU, bool OUTBF16>
__global__ __launch_bounds__(256) void fused_layer(
        const unsigned short* __restrict__ A,    // [M][128] bf16 node features
        const unsigned short* __restrict__ WT,   // [9*NOUT][128] bf16
        const float* __restrict__ bias,          // [NOUT]
        const int* __restrict__ off2,            // [NK+1]
        const int* __restrict__ esrc,            // [NE] src sorted by (rel,dst)
        void* __restrict__ outp, int M) {
    constexpr int CW = NOUT / 4;      // cols per wave (MFMA)
    constexpr int NJ = CW / 16;       // n-tiles per wave
    __shared__ unsigned short Asw[64 * 128];    // swizzled bf16 A-operand (16 KB)

    const int t = threadIdx.x;
    const int n0 = blockIdx.x * 64;
    const int bm = (M - n0 < 64) ? (M - n0) : 64;
    const int lane = t & 63;
    const int w = t >> 6;
    const int r15 = lane & 15;
    const int q = lane >> 4;

    const int key = t >> 2;          // local dst row 0..63
    const int sub = t & 3;           // col group: uints [sub*16, sub*16+16)
    const int kk = n0 + key;
    const bool kv = (kk < M);

    f32x4 acc[4][NJ] = {};

    auto do_mfma = [&](int rr) {
        #pragma unroll
        for (int ks = 0; ks < 4; ks++) {
            int c = (ks * 4 + q) ^ r15;
            bf16x8 af[4];
            #pragma unroll
            for (int i = 0; i < 4; i++)
                af[i] = *(const bf16x8*)((const char*)Asw + (i * 16 + r15) * 256 + (c << 4));
            #pragma unroll
            for (int j = 0; j < NJ; j++) {
                bf16x8 bf = *(const bf16x8*)(WT +
                    ((size_t)(rr * NOUT + w * CW + j * 16 + r15) << 7) + ks * 32 + q * 8);
                #pragma unroll
                for (int i = 0; i < 4; i++)
                    acc[i][j] = __builtin_amdgcn_mfma_f32_16x16x32_bf16(af[i], bf, acc[i][j], 0, 0, 0);
            }
        }
    };

    // prefetch relation-0 segment bounds (off critical path of pass 0)
    int e0 = kv ? off2[kk] : 0;
    int e1 = kv ? off2[kk + 1] : 0;

    // ---- self pass (K-chunk index 8): Asw = own feature rows ----
    #pragma unroll
    for (int kc = 0; kc < 4; kc++) {
        int g = t + kc * 256;           // 1024 chunks = 64 rows x 16
        int row = g >> 4, c = g & 15;
        uint4 v = make_uint4(0, 0, 0, 0);
        if (row < bm) v = *(const uint4*)(A + ((size_t)(n0 + row) << 7) + c * 8);
        *(uint4*)((char*)Asw + row * 256 + ((c ^ (row & 15)) << 4)) = v;
    }
    __syncthreads();
    do_mfma(8);

    // ---- relation passes ----
    for (int r = 0; r < 8; r++) {
        // prefetch next relation's bounds (consumed next iteration)
        int e0n = 0, e1n = 0;
        if (r < 7 && kv) {
            e0n = off2[(r + 1) * NN + kk];
            e1n = off2[(r + 1) * NN + kk + 1];
        }

        // register-accumulate own segment (no LDS touched -> overlaps prior MFMA)
        float a[32];
        #pragma unroll
        for (int i = 0; i < 32; i++) a[i] = 0.f;
        for (int e = e0; e < e1; ++e) {
            int s = esrc[e];
            const uint4* rp = (const uint4*)((const unsigned*)A + ((size_t)s << 6) + sub * 16);
            #pragma unroll
            for (int u4 = 0; u4 < 4; ++u4) {
                uint4 v = rp[u4];
                unsigned uu[4] = {v.x, v.y, v.z, v.w};
                #pragma unroll
                for (int j = 0; j < 4; ++j) {
                    a[u4 * 8 + j * 2 + 0] += __uint_as_float(uu[j] << 16);
                    a[u4 * 8 + j * 2 + 1] += __uint_as_float(uu[j] & 0xffff0000u);
                }
            }
        }
        __syncthreads();   // all waves done reading Asw from previous MFMA

        // pack to bf16 and write 4 swizzled 16B chunks (c = sub*4+c4)
        #pragma unroll
        for (int c4 = 0; c4 < 4; ++c4) {
            uint4 pv;
            pv.x = (unsigned)f2bf(a[c4 * 8 + 0]) | ((unsigned)f2bf(a[c4 * 8 + 1]) << 16);
            pv.y = (unsigned)f2bf(a[c4 * 8 + 2]) | ((unsigned)f2bf(a[c4 * 8 + 3]) << 16);
            pv.z = (unsigned)f2bf(a[c4 * 8 + 4]) | ((unsigned)f2bf(a[c4 * 8 + 5]) << 16);
            pv.w = (unsigned)f2bf(a[c4 * 8 + 6]) | ((unsigned)f2bf(a[c4 * 8 + 7]) << 16);
            int c = sub * 4 + c4;
            *(uint4*)((char*)Asw + key * 256 + ((c ^ (key & 15)) << 4)) = pv;
        }
        __syncthreads();

        do_mfma(r);
        e0 = e0n; e1 = e1n;
    }

    // ---- epilogue: + bias, optional ReLU, store ----
    #pragma unroll
    for (int j = 0; j < NJ; j++) {
        int col = w * CW + j * 16 + r15;
        float bv = bias[col];
        #pragma unroll
        for (int i = 0; i < 4; i++) {
            #pragma unroll
            for (int reg = 0; reg < 4; reg++) {
                int m = n0 + i * 16 + q * 4 + reg;
                if (m < M) {
                    float v = acc[i][j][reg] + bv;
                    if (RELU) v = fmaxf(v, 0.f);
                    if (OUTBF16)
                        ((unsigned short*)outp)[(size_t)m * NOUT + col] = f2bf(v);
                    else
                        ((float*)outp)[(size_t)m * NOUT + col] = v;
                }
            }
        }
    }
}

extern "C" void kernel_launch(void* const* d_in, const int* in_sizes, int n_in,
                              void* d_out, int out_size, void* d_ws, size_t ws_size,
                              hipStream_t stream) {
    const float* X   = (const float*)d_in[0];
    const int*   src = (const int*)d_in[1];
    const int*   dst = (const int*)d_in[2];
    const int*   et  = (const int*)d_in[3];
    const float* W1  = (const float*)d_in[4];
    const float* W1s = (const float*)d_in[5];
    const float* b1  = (const float*)d_in[6];
    const float* W2  = (const float*)d_in[7];
    const float* W2s = (const float*)d_in[8];
    const float* b2  = (const float*)d_in[9];
    float* out = (float*)d_out;

    // workspace carve (~34 MB)
    char* p = (char*)d_ws;
    unsigned short* Xbf = (unsigned short*)p; p += (size_t)NN * 128 * 2;       // 12.8 MB
    unsigned short* hbf = (unsigned short*)p; p += (size_t)NN * 128 * 2;       // 12.8 MB
    unsigned short* W1T = (unsigned short*)p; p += (size_t)9 * 128 * 128 * 2;  // 288 KB
    unsigned short* W2T = (unsigned short*)p; p += (size_t)9 * 64 * 128 * 2;   // 144 KB
    int* counts2 = (int*)p; p += (size_t)NK * 4;                               // 1.6 MB
    int* off2    = (int*)p; p += (size_t)(NK + 4) * 4;                         // 1.6 MB
    int* cursor2 = (int*)p; p += (size_t)NK * 4;                               // 1.6 MB
    int* esrc    = (int*)p; p += (size_t)NE * 4;                               // 2.56 MB
    int* bsum    = (int*)p; p += 512 * 4;
    int* bbase   = (int*)p; p += 512 * 4;

    // ---- single cooperative prep launch (CSR + dtype prep) ----
    void* args[] = {
        (void*)&X, (void*)&W1, (void*)&W1s, (void*)&W2, (void*)&W2s,
        (void*)&src, (void*)&dst, (void*)&et,
        (void*)&Xbf, (void*)&W1T, (void*)&W2T,
        (void*)&counts2, (void*)&off2, (void*)&cursor2, (void*)&esrc,
        (void*)&bsum, (void*)&bbase
    };
    hipLaunchCooperativeKernel((void*)prep_all, dim3(NPB), dim3(1024),
                               args, 0, stream);

    const int nblk = (NN + 63) / 64;  // 782

    // Layer 1: h = relu(agg1 + X@W1s + b1), stored bf16
    fused_layer<128, true, true><<<nblk, 256, 0, stream>>>(
        Xbf, W1T, b1, off2, esrc, hbf, NN);
    // Layer 2: out = agg2 + h@W2s + b2, fp32
    fused_layer<64, false, false><<<nblk, 256, 0, stream>>>(
        hbf, W2T, b2, off2, esrc, out, NN);
}

// Round 8
// 297.036 us; speedup vs baseline: 1.7977x; 1.7977x over previous
//
#include <hip/hip_runtime.h>
#include <hip/hip_bf16.h>
#include <stdint.h>

#define NN 50000     // nodes
#define NE 640000    // edges
#define NR 8         // relations
#define NK (NR * NN) // 400000 (rel,dst) keys
#define NPB 391      // scan blocks = ceil(NK/1024)

typedef short bf16x8 __attribute__((ext_vector_type(8)));
typedef float f32x4  __attribute__((ext_vector_type(4)));

__device__ __forceinline__ unsigned short f2bf(float f) {
    union { float f; unsigned u; } v; v.f = f;
    unsigned r = v.u + 0x7FFF + ((v.u >> 16) & 1);
    return (unsigned short)(r >> 16);
}

// ---------------- merged independent prep (memset + cvt + prepW1 + prepW2) ----------------
__global__ __launch_bounds__(256) void prep0_kernel(
        const float* __restrict__ X,
        const float* __restrict__ W1, const float* __restrict__ W1s,
        const float* __restrict__ W2, const float* __restrict__ W2s,
        unsigned short* __restrict__ Xbf,
        unsigned short* __restrict__ W1T, unsigned short* __restrict__ W2T,
        int* __restrict__ counts) {
    const int gid = blockIdx.x * 256 + threadIdx.x;
    const int gsz = gridDim.x * 256;

    // zero counts (uint4 = 16B)
    for (int i = gid; i < NK / 4; i += gsz)
        ((uint4*)counts)[i] = make_uint4(0, 0, 0, 0);

    // cvt X -> bf16, 8 floats per unit
    for (int i = gid; i < NN * 16; i += gsz) {
        const float4* pp = (const float4*)X + (size_t)i * 2;
        float4 a = pp[0], b = pp[1];
        uint4 o;
        o.x = (unsigned)f2bf(a.x) | ((unsigned)f2bf(a.y) << 16);
        o.y = (unsigned)f2bf(a.z) | ((unsigned)f2bf(a.w) << 16);
        o.z = (unsigned)f2bf(b.x) | ((unsigned)f2bf(b.y) << 16);
        o.w = (unsigned)f2bf(b.z) | ((unsigned)f2bf(b.w) << 16);
        ((uint4*)Xbf)[i] = o;
    }

    // W1T[(r*128+o)][k], r==8 -> W1s
    for (int i = gid; i < 9 * 128 * 128; i += gsz) {
        int k = i & 127, c = i >> 7;
        int r = c >> 7, o = c & 127;
        float v = (r < 8) ? W1[((size_t)r * 128 + k) * 128 + o]
                          : W1s[(size_t)k * 128 + o];
        W1T[i] = f2bf(v);
    }

    // W2T[(r*64+o)][k], r==8 -> W2s
    for (int i = gid; i < 9 * 64 * 128; i += gsz) {
        int k = i & 127, c = i >> 7;
        int r = c >> 6, o = c & 63;
        float v = (r < 8) ? W2[((size_t)r * 128 + k) * 64 + o]
                          : W2s[(size_t)k * 64 + o];
        W2T[i] = f2bf(v);
    }
}

// ---------------- CSR build over key = rel*NN + dst ----------------
__global__ void hist2_kernel(const int* __restrict__ dst, const int* __restrict__ et,
                             int* __restrict__ counts) {
    int e = blockIdx.x * 256 + threadIdx.x;
    if (e < NE) atomicAdd(&counts[et[e] * NN + dst[e]], 1);
}

__global__ __launch_bounds__(1024) void blocksum_kernel(const int* __restrict__ counts,
                                                        int* __restrict__ bsum, int n) {
    __shared__ int ws[16];
    int i = blockIdx.x * 1024 + threadIdx.x;
    int v = (i < n) ? counts[i] : 0;
    #pragma unroll
    for (int d = 32; d > 0; d >>= 1) v += __shfl_down(v, d, 64);
    int wid = threadIdx.x >> 6, lane = threadIdx.x & 63;
    if (lane == 0) ws[wid] = v;
    __syncthreads();
    if (threadIdx.x < 16) {
        int s = ws[threadIdx.x];
        #pragma unroll
        for (int d = 8; d > 0; d >>= 1) s += __shfl_down(s, d, 16);
        if (threadIdx.x == 0) bsum[blockIdx.x] = s;
    }
}

// local scan + inline base computation (replaces scanbase + scanlocal)
__global__ __launch_bounds__(1024) void scanlocal2_kernel(const int* __restrict__ counts,
                                                          const int* __restrict__ bsum,
                                                          int* __restrict__ offsets,
                                                          int* __restrict__ cursor, int n) {
    __shared__ int ws[16];
    __shared__ int wbase[16];
    __shared__ int base_sh;
    const int t = threadIdx.x, b = blockIdx.x;
    const int i = b * 1024 + t;
    const int lane = t & 63, wid = t >> 6;

    int v = (i < n) ? counts[i] : 0;
    int incl = v;
    #pragma unroll
    for (int d = 1; d < 64; d <<= 1) {
        int nv = __shfl_up(incl, d, 64);
        if (lane >= d) incl += nv;
    }
    if (lane == 63) ws[wid] = incl;
    __syncthreads();
    if (t < 16) {
        int s = ws[t], si = s;
        #pragma unroll
        for (int d = 1; d < 16; d <<= 1) {
            int nv = __shfl_up(si, d, 16);
            if (t >= d) si += nv;
        }
        wbase[t] = si - s;
    }
    __syncthreads();
    int local_excl = wbase[wid] + incl - v;

    // wave 0: base = sum of bsum[0..b)
    if (wid == 0) {
        int acc = 0;
        for (int j = lane; j < b; j += 64) acc += bsum[j];
        #pragma unroll
        for (int d = 32; d > 0; d >>= 1) acc += __shfl_down(acc, d, 64);
        if (lane == 0) base_sh = acc;
    }
    __syncthreads();

    if (i < n) {
        int excl = base_sh + local_excl;
        offsets[i] = excl;
        cursor[i]  = excl;
    }
    if (b == 0 && t == 0) offsets[NK] = NE;
}

__global__ void fill2_kernel(const int* __restrict__ src, const int* __restrict__ dst,
                             const int* __restrict__ et, int* __restrict__ cursor,
                             int* __restrict__ esrc) {
    int e = blockIdx.x * 256 + threadIdx.x;
    if (e < NE) {
        int pos = atomicAdd(&cursor[et[e] * NN + dst[e]], 1);
        esrc[pos] = src[e];
    }
}

// ---------------- Fused aggregate + transform layer ----------------
// Proven RB=64 shape (301.7 us baseline). Per block: 64 dst nodes, 256
// threads. Edges sorted by (rel,dst): atomic-free aggregation. Thread t owns
// dst row (t>>2), column group (t&3): 32 cols in registers over its segment,
// packed to bf16 into the XOR-swizzled Asw. MFMA-accumulates
// C[64][NOUT] += agg_r @ W[r]^T across r=0..7 plus self (idx 8).
template<int NOUT, bool RELU, bool OUTBF16>
__global__ __launch_bounds__(256) void fused_layer(
        const unsigned short* __restrict__ A,    // [M][128] bf16 node features
        const unsigned short* __restrict__ WT,   // [9*NOUT][128] bf16
        const float* __restrict__ bias,          // [NOUT]
        const int* __restrict__ off2,            // [NK+1]
        const int* __restrict__ esrc,            // [NE] src sorted by (rel,dst)
        void* __restrict__ outp, int M) {
    constexpr int CW = NOUT / 4;      // cols per wave (MFMA)
    constexpr int NJ = CW / 16;       // n-tiles per wave
    __shared__ unsigned short Asw[64 * 128];    // swizzled bf16 A-operand (16 KB)

    const int t = threadIdx.x;
    const int n0 = blockIdx.x * 64;
    const int bm = (M - n0 < 64) ? (M - n0) : 64;
    const int lane = t & 63;
    const int w = t >> 6;
    const int r15 = lane & 15;
    const int q = lane >> 4;

    const int key = t >> 2;          // local dst row 0..63
    const int sub = t & 3;           // col group: uints [sub*16, sub*16+16)
    const int kk = n0 + key;
    const bool kv = (kk < M);

    f32x4 acc[4][NJ] = {};

    auto do_mfma = [&](int rr) {
        #pragma unroll
        for (int ks = 0; ks < 4; ks++) {
            int c = (ks * 4 + q) ^ r15;
            bf16x8 af[4];
            #pragma unroll
            for (int i = 0; i < 4; i++)
                af[i] = *(const bf16x8*)((const char*)Asw + (i * 16 + r15) * 256 + (c << 4));
            #pragma unroll
            for (int j = 0; j < NJ; j++) {
                bf16x8 bf = *(const bf16x8*)(WT +
                    ((size_t)(rr * NOUT + w * CW + j * 16 + r15) << 7) + ks * 32 + q * 8);
                #pragma unroll
                for (int i = 0; i < 4; i++)
                    acc[i][j] = __builtin_amdgcn_mfma_f32_16x16x32_bf16(af[i], bf, acc[i][j], 0, 0, 0);
            }
        }
    };

    // prefetch relation-0 segment bounds (off critical path of pass 0)
    int e0 = kv ? off2[kk] : 0;
    int e1 = kv ? off2[kk + 1] : 0;

    // ---- self pass (K-chunk index 8): Asw = own feature rows ----
    #pragma unroll
    for (int kc = 0; kc < 4; kc++) {
        int g = t + kc * 256;           // 1024 chunks = 64 rows x 16
        int row = g >> 4, c = g & 15;
        uint4 v = make_uint4(0, 0, 0, 0);
        if (row < bm) v = *(const uint4*)(A + ((size_t)(n0 + row) << 7) + c * 8);
        *(uint4*)((char*)Asw + row * 256 + ((c ^ (row & 15)) << 4)) = v;
    }
    __syncthreads();
    do_mfma(8);

    // ---- relation passes ----
    for (int r = 0; r < 8; r++) {
        // prefetch next relation's bounds (consumed next iteration)
        int e0n = 0, e1n = 0;
        if (r < 7 && kv) {
            e0n = off2[(r + 1) * NN + kk];
            e1n = off2[(r + 1) * NN + kk + 1];
        }

        // register-accumulate own segment (no LDS touched -> overlaps prior MFMA)
        float a[32];
        #pragma unroll
        for (int i = 0; i < 32; i++) a[i] = 0.f;
        for (int e = e0; e < e1; ++e) {
            int s = esrc[e];
            const uint4* rp = (const uint4*)((const unsigned*)A + ((size_t)s << 6) + sub * 16);
            #pragma unroll
            for (int u4 = 0; u4 < 4; ++u4) {
                uint4 v = rp[u4];
                unsigned uu[4] = {v.x, v.y, v.z, v.w};
                #pragma unroll
                for (int j = 0; j < 4; ++j) {
                    a[u4 * 8 + j * 2 + 0] += __uint_as_float(uu[j] << 16);
                    a[u4 * 8 + j * 2 + 1] += __uint_as_float(uu[j] & 0xffff0000u);
                }
            }
        }
        __syncthreads();   // all waves done reading Asw from previous MFMA

        // pack to bf16 and write 4 swizzled 16B chunks (c = sub*4+c4)
        #pragma unroll
        for (int c4 = 0; c4 < 4; ++c4) {
            uint4 pv;
            pv.x = (unsigned)f2bf(a[c4 * 8 + 0]) | ((unsigned)f2bf(a[c4 * 8 + 1]) << 16);
            pv.y = (unsigned)f2bf(a[c4 * 8 + 2]) | ((unsigned)f2bf(a[c4 * 8 + 3]) << 16);
            pv.z = (unsigned)f2bf(a[c4 * 8 + 4]) | ((unsigned)f2bf(a[c4 * 8 + 5]) << 16);
            pv.w = (unsigned)f2bf(a[c4 * 8 + 6]) | ((unsigned)f2bf(a[c4 * 8 + 7]) << 16);
            int c = sub * 4 + c4;
            *(uint4*)((char*)Asw + key * 256 + ((c ^ (key & 15)) << 4)) = pv;
        }
        __syncthreads();

        do_mfma(r);
        e0 = e0n; e1 = e1n;
    }

    // ---- epilogue: + bias, optional ReLU, store ----
    #pragma unroll
    for (int j = 0; j < NJ; j++) {
        int col = w * CW + j * 16 + r15;
        float bv = bias[col];
        #pragma unroll
        for (int i = 0; i < 4; i++) {
            #pragma unroll
            for (int reg = 0; reg < 4; reg++) {
                int m = n0 + i * 16 + q * 4 + reg;
                if (m < M) {
                    float v = acc[i][j][reg] + bv;
                    if (RELU) v = fmaxf(v, 0.f);
                    if (OUTBF16)
                        ((unsigned short*)outp)[(size_t)m * NOUT + col] = f2bf(v);
                    else
                        ((float*)outp)[(size_t)m * NOUT + col] = v;
                }
            }
        }
    }
}

extern "C" void kernel_launch(void* const* d_in, const int* in_sizes, int n_in,
                              void* d_out, int out_size, void* d_ws, size_t ws_size,
                              hipStream_t stream) {
    const float* X   = (const float*)d_in[0];
    const int*   src = (const int*)d_in[1];
    const int*   dst = (const int*)d_in[2];
    const int*   et  = (const int*)d_in[3];
    const float* W1  = (const float*)d_in[4];
    const float* W1s = (const float*)d_in[5];
    const float* b1  = (const float*)d_in[6];
    const float* W2  = (const float*)d_in[7];
    const float* W2s = (const float*)d_in[8];
    const float* b2  = (const float*)d_in[9];
    float* out = (float*)d_out;

    // workspace carve (~34 MB)
    char* p = (char*)d_ws;
    unsigned short* Xbf = (unsigned short*)p; p += (size_t)NN * 128 * 2;       // 12.8 MB
    unsigned short* hbf = (unsigned short*)p; p += (size_t)NN * 128 * 2;       // 12.8 MB
    unsigned short* W1T = (unsigned short*)p; p += (size_t)9 * 128 * 128 * 2;  // 288 KB
    unsigned short* W2T = (unsigned short*)p; p += (size_t)9 * 64 * 128 * 2;   // 144 KB
    int* counts2 = (int*)p; p += (size_t)NK * 4;                               // 1.6 MB
    int* off2    = (int*)p; p += (size_t)(NK + 4) * 4;                         // 1.6 MB
    int* cursor2 = (int*)p; p += (size_t)NK * 4;                               // 1.6 MB
    int* esrc    = (int*)p; p += (size_t)NE * 4;                               // 2.56 MB
    int* bsum    = (int*)p; p += 512 * 4;
    int* bbase   = (int*)p; p += 512 * 4;

    // ---- prep: 5 launches, no grid.sync ----
    prep0_kernel<<<2048, 256, 0, stream>>>(X, W1, W1s, W2, W2s, Xbf, W1T, W2T, counts2);
    hist2_kernel<<<(NE + 255) / 256, 256, 0, stream>>>(dst, et, counts2);
    blocksum_kernel<<<NPB, 1024, 0, stream>>>(counts2, bsum, NK);
    scanlocal2_kernel<<<NPB, 1024, 0, stream>>>(counts2, bsum, off2, cursor2, NK);
    fill2_kernel<<<(NE + 255) / 256, 256, 0, stream>>>(src, dst, et, cursor2, esrc);

    const int nblk = (NN + 63) / 64;  // 782

    // Layer 1: h = relu(agg1 + X@W1s + b1), stored bf16
    fused_layer<128, true, true><<<nblk, 256, 0, stream>>>(
        Xbf, W1T, b1, off2, esrc, hbf, NN);
    // Layer 2: out = agg2 + h@W2s + b2, fp32
    fused_layer<64, false, false><<<nblk, 256, 0, stream>>>(
        hbf, W2T, b2, off2, esrc, out, NN);
}